// Round 2
// baseline (843.609 us; speedup 1.0000x reference)
//
#include <hip/hip_runtime.h>
#include <math.h>

// Merton jump diffusion path simulation.
// out[p][0] = S0; out[p][s+1] = S0 * exp( sum_{k<=s} log_ret[k][p] )
//
// R2: LDS-staged coalesced stores.
// R3: time-parallel block scan, 16 waves / 64 paths, occupancy 5.5% -> 77%.
// R4: counters showed occupancy fixed but BW stuck at 2 TB/s (25%), VALU 21%
//     -> latency still exposed: no loads in flight across the 3 barriers/tile,
//     and __syncthreads drains vmcnt(0) (m97 barrier-drain). Fixes:
//     (a) register-prefetch next tile at top of body, convert at bottom
//         (load->use distance = scan+stage+drain phases);
//     (b) raw s_barrier + lgkmcnt(0) only -- LDS-only coordination, so
//         prefetch loads + drain stores legally stay in flight;
//     (c) double-buffered stage tile -> 2 barriers/tile instead of 3.

#define N_STEPS 2048
#define N_PATHS 32768
#define ROW (N_STEPS + 1)

#define NWAVES 16
#define SUB 8                      // steps per lane per tile
#define TILE_S (NWAVES * SUB)      // 128
#define NTILES (N_STEPS / TILE_S)  // 16

#define DT_F 0.00048828125f                 // 1/2048 exact
#define C_DIFF_F 0.004419417382415922f      // SIGMA * sqrt(DT)
#define KAPPA_F 0.046027859908717f          // exp(0.045) - 1
#define ND_F (-4.8828125e-6f)               // -0.01 * DT

// LDS-visibility barrier WITHOUT vmcnt drain: this kernel's inter-wave
// communication is LDS-only (out is write-only, drained at kernel end),
// so global loads/stores may stay in flight across the barrier.
__device__ __forceinline__ void lds_barrier() {
    asm volatile("s_waitcnt lgkmcnt(0)" ::: "memory");
    __builtin_amdgcn_s_barrier();
}

__global__ __launch_bounds__(1024, 8) void merton_paths_kernel(
    const float* __restrict__ S0,
    const float* __restrict__ z_diff,
    const float* __restrict__ z_jump,
    const int* __restrict__ n_jumps,
    float* __restrict__ out) {
    const int tid  = threadIdx.x;
    const int lane = tid & 63;
    const int w    = tid >> 6;               // wave id 0..15 = time-chunk id
    const int pbase = blockIdx.x * 64;
    const int p     = pbase + lane;
    const float s0  = S0[0];

    // double-buffered staging tile [path][step]; stride 129 words = conflict-free
    __shared__ float stage[2][64][TILE_S + 1];   // 66048 B
    __shared__ float ws[NWAVES][64];             // 4096 B  (total 70144 <= 80K -> 2 blk/CU)

    const float r = __expf(ND_F);            // per-step lambda decay factor

    if (w == 0) out[p * ROW] = s0;           // int index ok (< 2^27)

    float zd[SUB], zj[SUB], val[SUB];
    int   nj[SUB];

    // ---- tile 0: load + convert to per-step log-returns val[] ----
    {
        int idx = (w * SUB) * N_PATHS + p;   // element index < 2^26
#pragma unroll
        for (int i = 0; i < SUB; ++i) {
            zd[i] = z_diff[idx];
            zj[i] = z_jump[idx];
            nj[i] = n_jumps[idx];
            idx += N_PATHS;
        }
        float e = __expf(ND_F * (float)(w * SUB));
#pragma unroll
        for (int i = 0; i < SUB; ++i) {
            float lam = 0.1f + 0.9f * e;
            e *= r;
            val[i] = (-(lam * KAPPA_F) * DT_F + C_DIFF_F * zd[i])
                   + sqrtf((float)nj[i]) * 0.3f * zj[i];
        }
    }

    float carry = 0.0f;                      // cumsum through all previous tiles

    for (int t = 0; t < NTILES; ++t) {
        // ---- prefetch tile t+1 (wraps to 0 on last iter; values discarded) ----
        const int tn = (t + 1 < NTILES) ? (t + 1) : 0;
        {
            int idx = (tn * TILE_S + w * SUB) * N_PATHS + p;
#pragma unroll
            for (int i = 0; i < SUB; ++i) {
                zd[i] = z_diff[idx];
                zj[i] = z_jump[idx];
                nj[i] = n_jumps[idx];
                idx += N_PATHS;
            }
        }

        // ---- in-place inclusive cumsum of current tile's val[] ----
        float acc = 0.0f;
#pragma unroll
        for (int i = 0; i < SUB; ++i) { acc += val[i]; val[i] = acc; }
        ws[w][lane] = acc;
        lds_barrier();                       // B1: ws visible

        // ---- block scan of the 16 chunk sums for my path ----
        float pre = carry, tot = 0.0f;
#pragma unroll
        for (int ww = 0; ww < NWAVES; ++ww) {
            float v = ws[ww][lane];
            pre += (ww < w) ? v : 0.0f;
            tot += v;
        }
        carry += tot;

        // ---- exp + stage into buffer (t&1) ----
        const int buf = t & 1;
#pragma unroll
        for (int i = 0; i < SUB; ++i)
            stage[buf][lane][w * SUB + i] = s0 * __expf(pre + val[i]);
        lds_barrier();                       // B2: stage visible

        // ---- drain: 4 rows/wave, 2 halves -> 256B coalesced stores ----
        {
            float* obase = out + pbase * ROW + 1 + t * TILE_S;
#pragma unroll
            for (int k = 0; k < 4; ++k) {
                int rr = w * 4 + k;
                float* orow = obase + rr * ROW;
                orow[lane]      = stage[buf][rr][lane];
                orow[lane + 64] = stage[buf][rr][lane + 64];
            }
        }

        // ---- convert prefetched regs -> next tile's val[] (vmcnt waits land
        //      here, a full scan+stage+drain after issue) ----
        float e = __expf(ND_F * (float)(tn * TILE_S + w * SUB));
#pragma unroll
        for (int i = 0; i < SUB; ++i) {
            float lam = 0.1f + 0.9f * e;
            e *= r;
            val[i] = (-(lam * KAPPA_F) * DT_F + C_DIFF_F * zd[i])
                   + sqrtf((float)nj[i]) * 0.3f * zj[i];
        }
    }
}

extern "C" void kernel_launch(void* const* d_in, const int* in_sizes, int n_in,
                              void* d_out, int out_size, void* d_ws, size_t ws_size,
                              hipStream_t stream) {
    const float* S0      = (const float*)d_in[0];
    const float* z_diff  = (const float*)d_in[1];
    const float* z_jump  = (const float*)d_in[2];
    const int*   n_jumps = (const int*)d_in[3];
    float* out = (float*)d_out;

    dim3 block(1024);
    dim3 grid(N_PATHS / 64);   // 512 blocks x 16 waves = 8192 waves, 2 blk/CU
    hipLaunchKernelGGL(merton_paths_kernel, grid, block, 0, stream,
                       S0, z_diff, z_jump, n_jumps, out);
}